// Round 2
// baseline (623.936 us; speedup 1.0000x reference)
//
#include <hip/hip_runtime.h>
#include <math.h>

// Problem dims (fixed by setup_inputs): (2, 1, 192, 192, 192) fp32
#define NW 192
#define NH 192
#define ND 192
#define NB 2
#define VOLF ((double)(NB) * ND * NH * NW)

#define TH 16          // output tile H
#define TW 16          // output tile W
#define HALO 5
#define LH (TH + 2*HALO)   // 26
#define LW (TW + 2*HALO)   // 26
#define DC 32              // D-chunk per block
#define SSTR 48            // LDS row stride for sa/sb: ≡16 (mod 32) → ≤2-way bank aliasing (free)

struct GaussK { float g[11]; };

__global__ void k_zero(float* out) { out[0] = 0.f; }

__global__ void k_final(float* out) {
    double s = (double)out[0];
    double m = 1.0 - s / VOLF;
    out[0] = (float)(m * m);
}

// Fully fused separable 3D blur + SSIM + mean. No workspace.
// Block: 256 threads = 16x16 (ty,tx). Grid: (12*12, ND/DC, NB).
__global__ __launch_bounds__(256)
void k_ssim_fused(const float* __restrict__ x,
                  const float* __restrict__ y,
                  const float* __restrict__ z,
                  const int* __restrict__ mod,
                  float* __restrict__ out, GaussK G) {
    __shared__ float sa[LH * SSTR];
    __shared__ float sb[LH * SSTR];
    __shared__ float tw0[LH * TW];
    __shared__ float tw1[LH * TW];
    __shared__ float tw2[LH * TW];
    __shared__ float tw3[LH * TW];
    __shared__ float tw4[LH * TW];
    __shared__ float wred[4];

    const int tid = threadIdx.x;
    const int tx = tid & 15;
    const int ty = tid >> 4;
    const int wt = blockIdx.x % (NW / TW);
    const int ht = blockIdx.x / (NW / TW);
    const int d0 = blockIdx.y * DC;
    const int n  = blockIdx.z;
    const int h0 = ht * TH;
    const int w0 = wt * TW;

    const float* bsel = (*mod == 0) ? z : y;
    const float* xb = x    + (size_t)n * ND * NH * NW;
    const float* bb = bsel + (size_t)n * ND * NH * NW;

    // Shift-register D accumulators: acc*[j] accumulates output depth (dd-5+j).
    // Weight of slice dd on out_d = dd-5+j is g[10-j] == g[j] (symmetric).
    float acc0[11], acc1[11], acc2[11], acc3[11], acc4[11];
#pragma unroll
    for (int j = 0; j < 11; ++j) { acc0[j]=0.f; acc1[j]=0.f; acc2[j]=0.f; acc3[j]=0.f; acc4[j]=0.f; }

    float sum = 0.f;

#pragma unroll 1
    for (int dd = d0 - HALO; dd < d0 + DC + HALO; ++dd) {
        if (dd >= 0 && dd < ND) {   // block-uniform condition (barriers inside are safe)
            const float* xs = xb + (size_t)dd * NH * NW;
            const float* bs = bb + (size_t)dd * NH * NW;
            // ---- stage a,b halo tile (26x26), zero-pad OOB ----
            for (int i = tid; i < LH * LW; i += 256) {
                int hh = i / LW;
                int ww = i - hh * LW;
                int gh = h0 - HALO + hh;
                int gw = w0 - HALO + ww;
                float av = 0.f, bv = 0.f;
                if ((unsigned)gh < (unsigned)NH && (unsigned)gw < (unsigned)NW) {
                    int gi = gh * NW + gw;
                    av = xs[gi];
                    bv = bs[gi];
                }
                sa[hh * SSTR + ww] = av;
                sb[hh * SSTR + ww] = bv;
            }
            __syncthreads();
            // ---- W-blur producing 5 fields at (26 x 16) points ----
            for (int p = tid; p < LH * TW; p += 256) {
                int hh = p >> 4;
                int wx = p & 15;
                float c0=0.f, c1=0.f, c2=0.f, c3=0.f, c4=0.f;
#pragma unroll
                for (int u = 0; u < 11; ++u) {
                    float g  = G.g[u];
                    float av = sa[hh * SSTR + wx + u];
                    float bv = sb[hh * SSTR + wx + u];
                    c0 += g * av;
                    c1 += g * bv;
                    c2 += g * av * av;
                    c3 += g * bv * bv;
                    c4 += g * av * bv;
                }
                tw0[p] = c0; tw1[p] = c1; tw2[p] = c2; tw3[p] = c3; tw4[p] = c4;
            }
            __syncthreads();
            // ---- H-blur into registers (one (ty,tx) point per thread) ----
            float v0=0.f, v1=0.f, v2=0.f, v3=0.f, v4=0.f;
#pragma unroll
            for (int v = 0; v < 11; ++v) {
                float g = G.g[v];
                int o = (ty + v) * TW + tx;
                v0 += g * tw0[o];
                v1 += g * tw1[o];
                v2 += g * tw2[o];
                v3 += g * tw3[o];
                v4 += g * tw4[o];
            }
            // ---- D accumulation (static-indexed shift registers) ----
#pragma unroll
            for (int j = 0; j < 11; ++j) {
                float g = G.g[j];   // == g[10-j]
                acc0[j] += g * v0;
                acc1[j] += g * v1;
                acc2[j] += g * v2;
                acc3[j] += g * v3;
                acc4[j] += g * v4;
            }
        }
        // ---- finalize out_d = dd - 5 (acc*[0] complete) ----
        int od = dd - HALO;
        if (od >= d0) {   // od < d0+DC guaranteed by loop bound
            float mu1 = acc0[0], mu2 = acc1[0];
            float mu1sq = mu1 * mu1, mu2sq = mu2 * mu2, mu12 = mu1 * mu2;
            float s1  = acc2[0] - mu1sq;
            float s2  = acc3[0] - mu2sq;
            float s12 = acc4[0] - mu12;
            const float C1 = 1e-4f;   // 0.01^2
            const float C2 = 9e-4f;   // 0.03^2
            float ssim = ((2.f * mu12 + C1) * (2.f * s12 + C2)) /
                         ((mu1sq + mu2sq + C1) * (s1 + s2 + C2));
            sum += ssim;
        }
        // ---- shift ----
#pragma unroll
        for (int j = 0; j < 10; ++j) {
            acc0[j] = acc0[j+1]; acc1[j] = acc1[j+1]; acc2[j] = acc2[j+1];
            acc3[j] = acc3[j+1]; acc4[j] = acc4[j+1];
        }
        acc0[10]=0.f; acc1[10]=0.f; acc2[10]=0.f; acc3[10]=0.f; acc4[10]=0.f;
    }

    // ---- block reduction → one atomic per block ----
    float v = sum;
#pragma unroll
    for (int off = 32; off > 0; off >>= 1) v += __shfl_down(v, off, 64);
    int lane = tid & 63;
    int wave = tid >> 6;
    if (lane == 0) wred[wave] = v;
    __syncthreads();
    if (tid == 0) {
        atomicAdd(out, wred[0] + wred[1] + wred[2] + wred[3]);
    }
}

extern "C" void kernel_launch(void* const* d_in, const int* in_sizes, int n_in,
                              void* d_out, int out_size, void* d_ws, size_t ws_size,
                              hipStream_t stream) {
    const float* x = (const float*)d_in[0];
    const float* y = (const float*)d_in[1];
    const float* z = (const float*)d_in[2];
    const int* modality = (const int*)d_in[3];
    float* out = (float*)d_out;

    // Gaussian taps (window=11, sigma=1.5), normalized — host-side.
    GaussK G;
    {
        double raw[11], s = 0.0;
        for (int i = 0; i < 11; ++i) {
            double dx = (double)(i - 5);
            raw[i] = exp(-(dx * dx) / (2.0 * 1.5 * 1.5));
            s += raw[i];
        }
        for (int i = 0; i < 11; ++i) G.g[i] = (float)(raw[i] / s);
    }

    k_zero<<<1, 1, 0, stream>>>(out);
    dim3 grid((NW / TW) * (NH / TH), ND / DC, NB);
    k_ssim_fused<<<grid, 256, 0, stream>>>(x, y, z, modality, out, G);
    k_final<<<1, 1, 0, stream>>>(out);
}

// Round 3
// 449.526 us; speedup vs baseline: 1.3880x; 1.3880x over previous
//
#include <hip/hip_runtime.h>
#include <math.h>

// Problem dims (fixed by setup_inputs): (2, 1, 192, 192, 192) fp32
#define NW 192
#define NH 192
#define ND 192
#define NB 2
#define SLICE (NH * NW)
#define VOLF ((double)(NB) * ND * NH * NW)

#define TH 16
#define TW 16
#define HALO 5
#define LH (TH + 2 * HALO)   // 26
#define LW (TW + 2 * HALO)   // 26
#define DC 24                // D-chunk: 8 chunks, grid 2304 blocks (9/CU)
#define ITERS (DC + 2 * HALO)  // 34
#define SSTR 48              // sa/sb row stride: ≡16 (mod 32) → ≤2-way aliasing (free)
#define WTILES (NW / TW)
#define HTILES (NH / TH)
#define NBLOCKS (WTILES * HTILES * (ND / DC) * NB)  // 2304

struct GaussK { float g[11]; };

__global__ void k_zero(float* p) { p[0] = 0.f; }

__global__ void k_final(float* out) {
    double s = (double)out[0];
    double m = 1.0 - s / VOLF;
    out[0] = (float)(m * m);
}

// Fused separable 3D blur + SSIM + mean, software-pipelined along D.
// Block: 256 threads = 16x16. Grid: (12*12, 8, 2).
__global__ __launch_bounds__(256)
void k_ssim_fused(const float* __restrict__ x, const float* __restrict__ y,
                  const float* __restrict__ z, const int* __restrict__ mod,
                  float* __restrict__ sum_buf, unsigned int* counter,
                  float* __restrict__ out, GaussK G) {
    __shared__ float sa[LH * SSTR];
    __shared__ float sb[LH * SSTR];
    __shared__ float tw0[LH * TW], tw1[LH * TW], tw2[LH * TW], tw3[LH * TW], tw4[LH * TW];
    __shared__ float wred[4];

    const int tid = threadIdx.x;
    const int tx = tid & 15, ty = tid >> 4;
    const int wt = blockIdx.x % WTILES, ht = blockIdx.x / WTILES;
    const int d0 = blockIdx.y * DC;
    const int n = blockIdx.z;
    const int h0 = ht * TH, w0 = wt * TW;

    const float* bsel = (*mod == 0) ? z : y;
    const float* xb = x + (size_t)n * ND * SLICE;
    const float* bb = bsel + (size_t)n * ND * SLICE;

    // ---- slice-invariant staging geometry (hoisted out of D-loop) ----
    int gi[3], saddr[3];
    bool pval[3];
#pragma unroll
    for (int k = 0; k < 3; ++k) {
        int p = tid + 256 * k;
        int pc = (p < LH * LW) ? p : 0;
        int hh = pc / LW, ww = pc - hh * LW;
        int gh = h0 - HALO + hh, gw = w0 - HALO + ww;
        pval[k] = (p < LH * LW) && ((unsigned)gh < (unsigned)NH) && ((unsigned)gw < (unsigned)NW);
        gi[k] = gh * NW + gw;
        saddr[k] = hh * SSTR + ww;
    }

    // prefetch registers
    float ra[3], rb[3];
    auto stage_load = [&](int dd) {
        bool ddok = ((unsigned)dd < (unsigned)ND);
        const float* xs = xb + (ptrdiff_t)dd * SLICE;
        const float* bs = bb + (ptrdiff_t)dd * SLICE;
#pragma unroll
        for (int k = 0; k < 3; ++k) {
            float av = 0.f, bv = 0.f;
            if (ddok && pval[k]) { av = xs[gi[k]]; bv = bs[gi[k]]; }
            ra[k] = av; rb[k] = bv;
        }
    };

    // D shift-register accumulators: acc*[j] holds output depth (dd-5+j),
    // weight of slice dd on it is g[10-j] == g[j] (symmetric kernel).
    float acc0[11], acc1[11], acc2[11], acc3[11], acc4[11];
#pragma unroll
    for (int j = 0; j < 11; ++j) { acc0[j]=0.f; acc1[j]=0.f; acc2[j]=0.f; acc3[j]=0.f; acc4[j]=0.f; }

    float sum = 0.f;
    stage_load(d0 - HALO);   // prologue: slice i=0

#pragma unroll 1
    for (int i = 0; i < ITERS; ++i) {
        // ---- commit staged registers to LDS ----
        sa[saddr[0]] = ra[0]; sb[saddr[0]] = rb[0];
        sa[saddr[1]] = ra[1]; sb[saddr[1]] = rb[1];
        if (tid < LH * LW - 512) { sa[saddr[2]] = ra[2]; sb[saddr[2]] = rb[2]; }
        __syncthreads();

        // ---- prefetch next slice (overlaps W+H blur below) ----
        if (i + 1 < ITERS) stage_load(d0 - HALO + i + 1);

        // ---- W-blur: 5 fields at 26x16 points ----
#pragma unroll
        for (int pass = 0; pass < 2; ++pass) {
            int p = tid + pass * 256;
            if (pass == 0 || tid < LH * TW - 256) {
                int hh = p >> 4, wx = p & 15;
                int sbase = hh * SSTR + wx;
                float c0=0.f, c1=0.f, c2=0.f, c3=0.f, c4=0.f;
#pragma unroll
                for (int u = 0; u < 11; ++u) {
                    float g = G.g[u];
                    float av = sa[sbase + u], bv = sb[sbase + u];
                    c0 += g * av;
                    c1 += g * bv;
                    c2 += g * (av * av);
                    c3 += g * (bv * bv);
                    c4 += g * (av * bv);
                }
                tw0[p]=c0; tw1[p]=c1; tw2[p]=c2; tw3[p]=c3; tw4[p]=c4;
            }
        }
        __syncthreads();

        // ---- H-blur into registers ----
        float v0=0.f, v1=0.f, v2=0.f, v3=0.f, v4=0.f;
#pragma unroll
        for (int v = 0; v < 11; ++v) {
            float g = G.g[v];
            int o = (ty + v) * TW + tx;
            v0 += g * tw0[o]; v1 += g * tw1[o]; v2 += g * tw2[o];
            v3 += g * tw3[o]; v4 += g * tw4[o];
        }

        // ---- D accumulation ----
#pragma unroll
        for (int j = 0; j < 11; ++j) {
            float g = G.g[j];
            acc0[j] += g*v0; acc1[j] += g*v1; acc2[j] += g*v2;
            acc3[j] += g*v3; acc4[j] += g*v4;
        }

        // ---- consume completed output depth od = d0 + i - 10 ----
        if (i >= 2 * HALO) {
            float mu1 = acc0[0], mu2 = acc1[0];
            float mu1sq = mu1 * mu1, mu2sq = mu2 * mu2, mu12 = mu1 * mu2;
            float s1  = acc2[0] - mu1sq;
            float s2  = acc3[0] - mu2sq;
            float s12 = acc4[0] - mu12;
            const float C1 = 1e-4f, C2 = 9e-4f;
            float ssim = ((2.f * mu12 + C1) * (2.f * s12 + C2)) /
                         ((mu1sq + mu2sq + C1) * (s1 + s2 + C2));
            sum += ssim;
        }

        // ---- shift ----
#pragma unroll
        for (int j = 0; j < 10; ++j) {
            acc0[j]=acc0[j+1]; acc1[j]=acc1[j+1]; acc2[j]=acc2[j+1];
            acc3[j]=acc3[j+1]; acc4[j]=acc4[j+1];
        }
        acc0[10]=0.f; acc1[10]=0.f; acc2[10]=0.f; acc3[10]=0.f; acc4[10]=0.f;
    }

    // ---- block reduction → one atomic per block ----
    float v = sum;
#pragma unroll
    for (int off = 32; off > 0; off >>= 1) v += __shfl_down(v, off, 64);
    if ((tid & 63) == 0) wred[tid >> 6] = v;
    __syncthreads();
    if (tid == 0) {
        float bsum = wred[0] + wred[1] + wred[2] + wred[3];
        atomicAdd(sum_buf, bsum);
        if (counter) {
            __threadfence();
            unsigned old = atomicAdd(counter, 1u);
            if (old == (unsigned)(NBLOCKS - 1)) {
                float total = atomicAdd(sum_buf, 0.f);  // fetch final sum
                double m = 1.0 - (double)total / VOLF;
                out[0] = (float)(m * m);
            }
        }
    }
}

extern "C" void kernel_launch(void* const* d_in, const int* in_sizes, int n_in,
                              void* d_out, int out_size, void* d_ws, size_t ws_size,
                              hipStream_t stream) {
    const float* x = (const float*)d_in[0];
    const float* y = (const float*)d_in[1];
    const float* z = (const float*)d_in[2];
    const int* modality = (const int*)d_in[3];
    float* out = (float*)d_out;

    GaussK G;
    {
        double raw[11], s = 0.0;
        for (int i = 0; i < 11; ++i) {
            double dx = (double)(i - 5);
            raw[i] = exp(-(dx * dx) / (2.0 * 1.5 * 1.5));
            s += raw[i];
        }
        for (int i = 0; i < 11; ++i) G.g[i] = (float)(raw[i] / s);
    }

    dim3 grid(WTILES * HTILES, ND / DC, NB);
    if (ws_size >= 256) {
        // sum at ws+0 (float), counter at ws+8; zeroed each launch (graph-safe memset node)
        float* sum_buf = (float*)d_ws;
        unsigned int* counter = (unsigned int*)((char*)d_ws + 8);
        hipMemsetAsync(d_ws, 0, 16, stream);
        k_ssim_fused<<<grid, 256, 0, stream>>>(x, y, z, modality, sum_buf, counter, out, G);
    } else {
        k_zero<<<1, 1, 0, stream>>>(out);
        k_ssim_fused<<<grid, 256, 0, stream>>>(x, y, z, modality, out, nullptr, out, G);
        k_final<<<1, 1, 0, stream>>>(out);
    }
}